// Round 14
// baseline (2241.769 us; speedup 1.0000x reference)
//
#include <hip/hip_runtime.h>
#include <hip/hip_bf16.h>

typedef unsigned int u32;
typedef unsigned short u16;

constexpr int NHW = 4096;

// identity on sane data; maps NaN->0, clamps to +/-1e20
__device__ __forceinline__ float sanit(float v){
    v = (v == v) ? v : 0.0f;
    return fminf(fmaxf(v, -1e20f), 1e20f);
}
__device__ __forceinline__ float sigm(float x){ return 1.0f/(1.0f + expf(-x)); }
__device__ __forceinline__ float lrelu(float x){ return x > 0.f ? x : 0.01f*x; }

// ---------------- weight reorganization (f32 inputs -> f32 scratch in d_out) ----------------
__global__ __launch_bounds__(256) void k_reorg_wg(const float* __restrict__ wg, float4* __restrict__ out){
    int idx = blockIdx.x*256 + threadIdx.x;      // 192*9*64 = 110592
    if (idx >= 192*9*64) return;
    int hc = idx & 63;
    int tap = (idx >> 6) % 9;
    int ic = idx / (9*64);
    float4 v;
    v.x = sanit(wg[((0*64+hc)*192 + ic)*9 + tap]);
    v.y = sanit(wg[((1*64+hc)*192 + ic)*9 + tap]);
    v.z = sanit(wg[((2*64+hc)*192 + ic)*9 + tap]);
    v.w = sanit(wg[((3*64+hc)*192 + ic)*9 + tap]);
    out[idx] = v;
}

__global__ __launch_bounds__(256) void k_reorg_conv(const float* __restrict__ w, float* __restrict__ out,
                                                    int cin, int cout){
    // in [cout][cin][9] -> out [(ic*9+tap)*cout + oc]
    int idx = blockIdx.x*256 + threadIdx.x;
    if (idx >= cin*cout*9) return;
    int oc = idx % cout;
    int tap = (idx / cout) % 9;
    int ic = idx / (cout*9);
    out[idx] = sanit(w[(oc*cin + ic)*9 + tap]);
}

__global__ __launch_bounds__(256) void k_fm(const float* __restrict__ flow, const float* __restrict__ fhigh,
                                            float* __restrict__ Fm, float* __restrict__ FmT){
    int idx = blockIdx.x*256 + threadIdx.x;     // 4096
    if (idx >= 64*64) return;
    int j = idx & 63, i = idx >> 6;
    float s = (i==j) ? 1.0f : 0.0f;
    for (int t=0; t<24; ++t) s = fmaf(sanit(flow[i*24 + t]), sanit(fhigh[t*64 + j]), s);
    s = sanit(s);
    Fm[i*64+j] = s; FmT[j*64+i] = s;
}

// ---------------- gates conv (192->256, 3x3) + fused 1x1 input proj + LSTM pointwise ----------------
__global__ __launch_bounds__(256) void k_gates(
    const float* __restrict__ x, const float* __restrict__ win, const float* __restrict__ bin,
    const float* __restrict__ h, const float* __restrict__ m,
    const float* __restrict__ c, const float4* __restrict__ Wg4, const float* __restrict__ bg,
    float* __restrict__ c_out, float* __restrict__ hl_out)
{
    __shared__ float smem[48*3*68];
    const int bid = blockIdx.x;
    const int b = bid >> 6, y = bid & 63;
    const int t = threadIdx.x;
    const int hc = t & 63, xg = t >> 6, x0 = xg*16;

    float acc0[16], acc1[16], acc2[16], acc3[16];
    #pragma unroll
    for (int i=0;i<16;++i){acc0[i]=0.f;acc1[i]=0.f;acc2[i]=0.f;acc3[i]=0.f;}

    for (int ci=0; ci<4; ++ci){
        __syncthreads();
        for (int it = t; it < 48*3*68; it += 256){
            int icl = it / 204;
            int rem = it - icl*204;
            int dy = rem / 68;
            int xi = rem - dy*68;
            int xx = xi - 1;
            int ys = y + dy - 1;
            float v = 0.f;
            if (((unsigned)xx < 64u) && ((unsigned)ys < 64u)){
                int icg = ci*48 + icl;
                int off = ys*64 + xx;
                if (icg < 64){
                    // fused input_conv_3 (1x1): xproj = W_in @ x + b_in
                    float x0v = sanit(x[(b*3+0)*NHW + off]);
                    float x1v = sanit(x[(b*3+1)*NHW + off]);
                    float x2v = sanit(x[(b*3+2)*NHW + off]);
                    v = sanit(win[icg*3])*x0v + sanit(win[icg*3+1])*x1v
                      + sanit(win[icg*3+2])*x2v + sanit(bin[icg]);
                } else if (icg < 128){
                    v = sanit(h[(b*64+icg-64)*NHW + off]);
                } else {
                    v = sanit(m[(b*64+icg-128)*NHW + off]);
                }
            }
            smem[it] = v;
        }
        __syncthreads();

        const float4* wp = Wg4 + (ci*48*9)*64 + hc;
        #pragma unroll 1
        for (int icl=0; icl<48; ++icl){
            #pragma unroll
            for (int dy=0; dy<3; ++dy){
                float r[20];
                const float4* rp = (const float4*)(&smem[icl*204 + dy*68 + x0]);
                #pragma unroll
                for (int q=0;q<5;++q){ float4 v4 = rp[q];
                    r[4*q]=v4.x; r[4*q+1]=v4.y; r[4*q+2]=v4.z; r[4*q+3]=v4.w; }
                #pragma unroll
                for (int dx=0; dx<3; ++dx){
                    float4 wv = wp[(icl*9 + dy*3 + dx)*64];
                    #pragma unroll
                    for (int xx=0; xx<16; ++xx){
                        float iv = r[xx+dx];
                        acc0[xx] = fmaf(wv.x, iv, acc0[xx]);
                        acc1[xx] = fmaf(wv.y, iv, acc1[xx]);
                        acc2[xx] = fmaf(wv.z, iv, acc2[xx]);
                        acc3[xx] = fmaf(wv.w, iv, acc3[xx]);
                    }
                }
            }
        }
    }

    float bi = sanit(bg[hc]), bf_ = sanit(bg[64+hc]);
    float bg_ = sanit(bg[128+hc]), bo = sanit(bg[192+hc]);
    const int base = (b*64+hc)*NHW + y*64 + x0;
    float cv[16];
    { const float4* cp = (const float4*)(c + base);      // c input is f32
      #pragma unroll
      for (int q=0;q<4;++q){ float4 v4 = cp[q];
          cv[4*q]=v4.x; cv[4*q+1]=v4.y; cv[4*q+2]=v4.z; cv[4*q+3]=v4.w; } }
    float cw[16], hw_[16];
    #pragma unroll
    for (int xx=0; xx<16; ++xx){
        float civ = sanit(cv[xx]);
        float iv = sigm(sanit(acc0[xx])+bi);
        float fv = sigm(sanit(acc1[xx])+bf_);
        float gv = tanhf(sanit(acc2[xx])+bg_);
        float ov = sigm(sanit(acc3[xx])+bo);
        float cn = fv*civ + iv*gv;
        cw[xx] = cn;
        hw_[xx] = ov*tanhf(cn);
    }
    float4* co = (float4*)(c_out + base);
    float4* ho = (float4*)(hl_out + base);
    #pragma unroll
    for (int q=0;q<4;++q){
        co[q] = make_float4(cw[4*q], cw[4*q+1], cw[4*q+2], cw[4*q+3]);
        ho[q] = make_float4(hw_[4*q], hw_[4*q+1], hw_[4*q+2], hw_[4*q+3]);
    }
}

// ---------------- conv_m (64->64, 3x3) + m_next pointwise — runs LAST, reads f32 c_next ----------------
__global__ __launch_bounds__(256) void k_convm(
    const float* __restrict__ cnx, const float* __restrict__ wm, const float* __restrict__ bm,
    float* __restrict__ m_out)
{
    __shared__ float smem[64*3*68];
    const int bid = blockIdx.x;
    const int b = bid >> 6, y = bid & 63;
    const int t = threadIdx.x;
    const int oc = t & 63, xg = t >> 6, x0 = xg*16;

    for (int it = t; it < 64*3*68; it += 256){
        int icl = it / 204;
        int rem = it - icl*204;
        int dy = rem / 68;
        int xi = rem - dy*68;
        int xx = xi - 1, ys = y + dy - 1;
        float v = 0.f;
        if (((unsigned)xx < 64u) && ((unsigned)ys < 64u))
            v = cnx[(b*64+icl)*NHW + ys*64 + xx];     // my own f32 c_next
        smem[it] = v;
    }
    __syncthreads();

    float acc[16];
    #pragma unroll
    for (int i=0;i<16;++i) acc[i]=0.f;
    #pragma unroll 1
    for (int ic=0; ic<64; ++ic){
        const float* wrow = wm + (oc*64 + ic)*9;   // w_m f32 [64][64][3][3]
        #pragma unroll
        for (int dy=0; dy<3; ++dy){
            float r[20];
            const float4* rp = (const float4*)(&smem[ic*204 + dy*68 + x0]);
            #pragma unroll
            for (int q=0;q<5;++q){ float4 v4=rp[q]; r[4*q]=v4.x;r[4*q+1]=v4.y;r[4*q+2]=v4.z;r[4*q+3]=v4.w; }
            #pragma unroll
            for (int dx=0; dx<3; ++dx){
                float wv = sanit(wrow[dy*3 + dx]);
                #pragma unroll
                for (int xx=0; xx<16; ++xx) acc[xx] = fmaf(wv, r[xx+dx], acc[xx]);
            }
        }
    }
    float bmv = sanit(bm[oc]);
    const int base = (b*64+oc)*NHW + y*64 + x0;
    float cv[16];
    { const float4* cp = (const float4*)(cnx + base);
      #pragma unroll
      for (int q=0;q<4;++q){ float4 v4=cp[q]; cv[4*q]=v4.x;cv[4*q+1]=v4.y;cv[4*q+2]=v4.z;cv[4*q+3]=v4.w; } }
    float4* mo = (float4*)(m_out + base);
    #pragma unroll
    for (int q=0;q<4;++q){
        float m0 = sigm(sanit(acc[4*q+0])+bmv)*tanhf(cv[4*q+0]);
        float m1 = sigm(sanit(acc[4*q+1])+bmv)*tanhf(cv[4*q+1]);
        float m2 = sigm(sanit(acc[4*q+2])+bmv)*tanhf(cv[4*q+2]);
        float m3 = sigm(sanit(acc[4*q+3])+bmv)*tanhf(cv[4*q+3]);
        mo[q] = make_float4(m0,m1,m2,m3);
    }
}

// ---------------- 4x4 avg pool (reads f32 h_lstm) ----------------
__global__ __launch_bounds__(256) void k_pool(const float* __restrict__ hl, float* __restrict__ p){
    int idx = blockIdx.x*256 + threadIdx.x;     // 32*64*256
    int px = idx & 15, py = (idx>>4) & 15, ch = (idx>>8) & 63, b = idx >> 14;
    const float* src = hl + (b*64+ch)*NHW + (py*4)*64 + px*4;
    float s = 0.f;
    #pragma unroll
    for (int dy=0;dy<4;++dy)
        #pragma unroll
        for (int dx=0;dx<4;++dx) s += src[dy*64 + dx];
    p[idx] = s * 0.0625f;
}

// ---------------- encoder conv (64->32, 3x3 on 16x16) ----------------
__global__ __launch_bounds__(512) void k_encconv(const float* __restrict__ p, const float* __restrict__ We,
        const float* __restrict__ bb, float* __restrict__ e){
    __shared__ float smem[64*3*18];
    int bid = blockIdx.x;
    int b = bid >> 4, py = bid & 15;
    int t = threadIdx.x;
    for (int it = t; it < 64*3*18; it += 512){
        int ic = it / 54;
        int rem = it - ic*54;
        int dy = rem / 18;
        int xi = rem - dy*18;
        int xx = xi-1, ys = py+dy-1;
        float v = 0.f;
        if (((unsigned)xx<16u)&&((unsigned)ys<16u)) v = p[(b*64+ic)*256 + ys*16+xx];
        smem[it] = v;
    }
    __syncthreads();
    int oc = t & 31, px = t >> 5;
    float acc = sanit(bb[oc]);
    #pragma unroll 1
    for (int ic=0; ic<64; ++ic){
        #pragma unroll
        for (int dy=0; dy<3; ++dy){
            const float* row = &smem[ic*54 + dy*18];
            #pragma unroll
            for (int dx=0; dx<3; ++dx)
                acc = fmaf(We[(ic*9+dy*3+dx)*32 + oc], row[px+dx], acc);
        }
    }
    e[b*8192 + oc*256 + py*16 + px] = lrelu(sanit(acc));
}

// ---------------- encoder linear 8192->64 + LayerNorm (f32 weights) ----------------
__global__ __launch_bounds__(1024) void k_enclin(const float* __restrict__ e, const float* __restrict__ elw,
        const float* __restrict__ lb, const float* __restrict__ lg, const float* __restrict__ lbeta,
        float* __restrict__ enc){
    __shared__ float sums[16*64];
    int b = blockIdx.x;
    int t = threadIdx.x;
    int s = t & 63, part = t >> 6;
    float acc = 0.f;
    const float* eb = e + b*8192 + part*512;
    const float* wb = elw + s*8192 + part*512;   // enc_lin_w is [64][8192] row-major
    for (int k=0; k<512; ++k)
        acc = fmaf(eb[k], sanit(wb[k]), acc);
    sums[part*64 + s] = acc;
    __syncthreads();
    if (t < 64){
        float v = sanit(lb[t]);
        #pragma unroll
        for (int q=0;q<16;++q) v += sums[q*64 + t];
        v = sanit(v);
        float sm = v, sq = v*v;
        #pragma unroll
        for (int o=32;o>=1;o>>=1){ sm += __shfl_xor(sm,o,64); sq += __shfl_xor(sq,o,64); }
        float mu = sm*(1.f/64.f);
        float var = fmaxf(sq*(1.f/64.f) - mu*mu, 0.f);
        enc[b*64+t] = sanit((v-mu)*rsqrtf(var+1e-5f)*sanit(lg[t])+sanit(lbeta[t]));
    }
}

// ---------------- KF nonlinearity + state_pred ----------------
__global__ __launch_bounds__(128) void k_nlspred(const float* __restrict__ kf,
        const float* __restrict__ nl1w, const float* __restrict__ nl1b,
        const float* __restrict__ lng, const float* __restrict__ lnb,
        const float* __restrict__ nl2w, const float* __restrict__ nl2b,
        const float* __restrict__ nlweight, const float* __restrict__ Fm,
        float* __restrict__ spred){
    __shared__ float ks[64], hid[128], hln[128];
    int b = blockIdx.x, t = threadIdx.x;
    if (t < 64) ks[t] = sanit(kf[b*64 + t]);
    __syncthreads();
    {
        float a = sanit(nl1b[t]);
        for (int k=0;k<64;++k) a = fmaf(ks[k], sanit(nl1w[t*64 + k]), a);
        hid[t] = sanit(a);
    }
    __syncthreads();
    {
        float sm=0.f, sq=0.f;
        for (int k=0;k<128;++k){ float v=hid[k]; sm+=v; sq+=v*v; }
        float mu = sm*(1.f/128.f), var = fmaxf(sq*(1.f/128.f)-mu*mu, 0.f);
        float nv = (hid[t]-mu)*rsqrtf(var+1e-5f)*sanit(lng[t])+sanit(lnb[t]);
        hln[t] = lrelu(sanit(nv));
    }
    __syncthreads();
    if (t < 64){
        float a = sanit(nl2b[t]);
        for (int k=0;k<128;++k) a = fmaf(hln[k], sanit(nl2w[t*128 + k]), a);
        float sp = sigm(sanit(nlweight[0])) * tanhf(sanit(a));
        for (int k=0;k<64;++k) sp = fmaf(ks[k], sanit(Fm[t*64+k]), sp);
        spred[b*64+t] = sanit(sp);
    }
}

// ---------------- EKF core (f32 in/out) ----------------
__global__ __launch_bounds__(256) void k_ekf(
    const float* __restrict__ kfcov, const float* __restrict__ FmG, const float* __restrict__ FmTG,
    const float* __restrict__ logQ, const float* __restrict__ logR,
    const float* __restrict__ enc, const float* __restrict__ spred,
    float* __restrict__ kfn_f32, float* __restrict__ kfs_out, float* __restrict__ cov_out)
{
    __shared__ float A[64*65];    // cov -> Tm -> K
    __shared__ float P[64*65];    // P_pred
    __shared__ float Sm[64*65];   // S -> Sinv -> TP
    __shared__ float rdv[64], innov[64], fcol[64];
    int b = blockIdx.x, t = threadIdx.x;
    int j = t & 63, ig = t >> 6;

    for (int o=t; o<4096; o+=256){
        int k = o >> 6, jj = o & 63;
        A[k*65+jj] = sanit(kfcov[b*4096 + o]);
    }
    if (t < 64){
        rdv[t] = sanit(expf(sanit(logR[t])));
        innov[t] = sanit(sanit(enc[b*64+t]) - sanit(spred[b*64+t]));
    }
    __syncthreads();

    // Tm = Fm @ cov
    float acc[16];
    #pragma unroll
    for (int r=0;r<16;++r) acc[r]=0.f;
    for (int k=0;k<64;++k){
        float cv = A[k*65+j];
        #pragma unroll
        for (int r=0;r<16;++r) acc[r] = fmaf(sanit(FmG[(ig*16+r)*64+k]), cv, acc[r]);
    }
    __syncthreads();
    #pragma unroll
    for (int r=0;r<16;++r) A[(ig*16+r)*65+j] = sanit(acc[r]);
    __syncthreads();

    // P = Tm @ Fm^T + diag(Q); Sm = P + diag(R) + 1e-5 I
    #pragma unroll
    for (int r=0;r<16;++r) acc[r]=0.f;
    for (int k=0;k<64;++k){
        float fv = sanit(FmTG[k*64+j]);
        #pragma unroll
        for (int r=0;r<16;++r) acc[r] = fmaf(A[(ig*16+r)*65+k], fv, acc[r]);
    }
    #pragma unroll
    for (int r=0;r<16;++r){
        int i = ig*16+r;
        float v = sanit(acc[r]);
        if (i==j) v += sanit(expf(sanit(logQ[i])));
        P[i*65+j] = v;
        Sm[i*65+j] = v + ((i==j) ? (rdv[j] + 1e-5f) : 0.f);
    }
    __syncthreads();

    // in-place Gauss-Jordan inversion of Sm (diag-dominant, no pivoting).
    for (int k=0;k<64;++k){
        float d = Sm[k*65+k];
        if (fabsf(d) < 1e-20f) d = (d < 0.f) ? -1e-20f : 1e-20f;
        float pv = 1.0f / d;
        float skj = (j==k) ? pv : Sm[k*65+j]*pv;
        if (ig == 0) fcol[j] = Sm[j*65+k];
        __syncthreads();
        #pragma unroll
        for (int r=0;r<16;++r){
            int i = ig*16+r;
            float nv;
            if (i == k)      nv = skj;
            else if (j == k) nv = -fcol[i]*pv;
            else             nv = fmaf(-fcol[i], skj, Sm[i*65+j]);
            Sm[i*65+j] = sanit(nv);
        }
        __syncthreads();
    }

    // K = P @ Sinv -> A
    #pragma unroll
    for (int r=0;r<16;++r) acc[r]=0.f;
    for (int k=0;k<64;++k){
        float sv = Sm[k*65+j];
        #pragma unroll
        for (int r=0;r<16;++r) acc[r] = fmaf(P[(ig*16+r)*65+k], sv, acc[r]);
    }
    __syncthreads();
    #pragma unroll
    for (int r=0;r<16;++r) A[(ig*16+r)*65+j] = sanit(acc[r]);
    __syncthreads();

    // kf_state_next = spred + K @ innov
    if (t < 64){
        float kn = sanit(spred[b*64+t]);
        for (int k2=0;k2<64;++k2) kn = fmaf(A[t*65+k2], innov[k2], kn);
        kn = sanit(kn);
        kfn_f32[b*64+t] = kn;
        kfs_out[b*64+t] = kn;
    }

    // TP = P - K@P -> Sm
    #pragma unroll
    for (int r=0;r<16;++r) acc[r]=0.f;
    for (int k=0;k<64;++k){
        float pvj = P[k*65+j];
        #pragma unroll
        for (int r=0;r<16;++r) acc[r] = fmaf(A[(ig*16+r)*65+k], pvj, acc[r]);
    }
    __syncthreads();
    #pragma unroll
    for (int r=0;r<16;++r) Sm[(ig*16+r)*65+j] = sanit(P[(ig*16+r)*65+j] - acc[r]);
    __syncthreads();

    // cov[i][j] = TP[i][j] - sum_k TP[i][k]*K[j][k] + sum_k K[i][k]*R[k]*K[j][k]
    #pragma unroll
    for (int r=0;r<16;++r){
        int i = ig*16+r;
        float s1 = 0.f, s2 = 0.f;
        for (int k=0;k<64;++k){
            float kjk = A[j*65+k];
            s1 = fmaf(Sm[i*65+k], kjk, s1);
            s2 = fmaf(A[i*65+k]*rdv[k], kjk, s2);
        }
        cov_out[b*4096 + i*64 + j] = sanit(Sm[i*65+j] - s1 + s2);
    }
}

// ---------------- decoder linear 64->8192 (f32 weights) ----------------
__global__ __launch_bounds__(256) void k_declin(const float* __restrict__ kfn, const float* __restrict__ dlw,
        const float* __restrict__ db, float* __restrict__ dlin){
    __shared__ float ks[64];
    int bid = blockIdx.x;
    int b = bid >> 5;
    int j = (bid & 31)*256 + threadIdx.x;
    if (threadIdx.x < 64) ks[threadIdx.x] = sanit(kfn[b*64 + threadIdx.x]);
    __syncthreads();
    float a = sanit(db[j]);
    const float* wr = dlw + j*64;               // dec_lin_w is [8192][64] row-major
    for (int k=0;k<64;++k) a = fmaf(ks[k], sanit(wr[k]), a);
    dlin[b*8192 + j] = lrelu(sanit(a));
}

// ---------------- decoder conv (32->64, 3x3) + fused bilinear upsample + final h_next ----------------
// IN-PLACE on hbuf (= f32 out_h region holding h_lstm): each thread reads exactly the
// 16 f32 elements it later writes; all (block,thread) address sets disjoint -> safe.
__global__ __launch_bounds__(256) void k_decconv(
    const float* __restrict__ dlin, const float* __restrict__ Wd, const float* __restrict__ bd,
    float* hbuf, const float* __restrict__ horig,
    const float* __restrict__ alpha_p, const float* __restrict__ resw_p)
{
    __shared__ float smem[32*3*68];
    int bid = blockIdx.x;
    int b = bid >> 6, y = bid & 63;
    int t = threadIdx.x;
    int oc = t & 63, xg = t >> 6, x0 = xg*16;

    for (int it=t; it<32*3*68; it+=256){
        int icl = it / 204;
        int rem = it - icl*204;
        int dy = rem / 68;
        int xi = rem - dy*68;
        int xx = xi-1, ys = y+dy-1;
        float v = 0.f;
        if (((unsigned)xx<64u)&&((unsigned)ys<64u)){
            // fused bilinear upsample 16x16 -> 64x64 (align_corners=False, clamped)
            float sy = (ys + 0.5f)*0.25f - 0.5f;
            float sx = (xx + 0.5f)*0.25f - 0.5f;
            float y0f = floorf(sy), x0f = floorf(sx);
            float fy = sy - y0f, fx = sx - x0f;
            int y0 = (int)y0f, x0i = (int)x0f;
            int y1 = min(max(y0+1,0),15), x1 = min(max(x0i+1,0),15);
            y0 = min(max(y0,0),15); x0i = min(max(x0i,0),15);
            const float* dp = dlin + (b*32+icl)*256;
            float v00 = sanit(dp[y0*16+x0i]), v01 = sanit(dp[y0*16+x1]);
            float v10 = sanit(dp[y1*16+x0i]), v11 = sanit(dp[y1*16+x1]);
            float va = v00 + fx*(v01-v00);
            float vb = v10 + fx*(v11-v10);
            v = va + fy*(vb-va);
        }
        smem[it] = v;
    }
    __syncthreads();

    float acc[16];
    #pragma unroll
    for (int i=0;i<16;++i) acc[i]=0.f;
    #pragma unroll 1
    for (int ic=0; ic<32; ++ic){
        #pragma unroll
        for (int dy=0; dy<3; ++dy){
            float r[20];
            const float4* rp = (const float4*)(&smem[ic*204 + dy*68 + x0]);
            #pragma unroll
            for (int q=0;q<5;++q){ float4 v4=rp[q]; r[4*q]=v4.x;r[4*q+1]=v4.y;r[4*q+2]=v4.z;r[4*q+3]=v4.w; }
            #pragma unroll
            for (int dx=0; dx<3; ++dx){
                float wv = sanit(Wd[(ic*9+dy*3+dx)*64 + oc]);
                #pragma unroll
                for (int xx=0;xx<16;++xx) acc[xx] = fmaf(wv, r[xx+dx], acc[xx]);
            }
        }
    }
    float bdv = sanit(bd[oc]);
    float alpha = sigm(sanit(alpha_p[0]));
    float resw = sigm(sanit(resw_p[0]));
    int base = (b*64+oc)*NHW + y*64 + x0;
    float hlv[16], hov[16];
    { const float4* hp2 = (const float4*)(hbuf + base);
      #pragma unroll
      for (int q=0;q<4;++q){ float4 v4=hp2[q]; hlv[4*q]=v4.x;hlv[4*q+1]=v4.y;hlv[4*q+2]=v4.z;hlv[4*q+3]=v4.w; } }
    { const float4* gp = (const float4*)(horig + base);   // f32 input h
      #pragma unroll
      for (int q=0;q<4;++q){ float4 v4=gp[q]; hov[4*q]=v4.x;hov[4*q+1]=v4.y;hov[4*q+2]=v4.z;hov[4*q+3]=v4.w; } }
    float hn[16];
    #pragma unroll
    for (int xx=0; xx<16; ++xx){
        float dec = lrelu(sanit(acc[xx]+bdv));
        hn[xx] = hlv[xx]*(1.f-alpha) + dec*alpha + resw*sanit(hov[xx]);
    }
    float4* hp = (float4*)(hbuf + base);
    #pragma unroll
    for (int q=0;q<4;++q)
        hp[q] = make_float4(hn[4*q], hn[4*q+1], hn[4*q+2], hn[4*q+3]);
}

extern "C" void kernel_launch(void* const* d_in, const int* in_sizes, int n_in,
                              void* d_out, int out_size, void* d_ws, size_t ws_size,
                              hipStream_t stream)
{
    (void)in_sizes; (void)n_in; (void)out_size; (void)d_ws; (void)ws_size;
    // Inputs: float32 (PROVEN: in_npz 100.9MB > 54.6MB bf16-raw ceiling).
    // Outputs: float32 (PROVEN: out_npz 93.3MB > 50.6MB bf16-raw ceiling).
    const float* x    = (const float*)d_in[0];
    const float* h    = (const float*)d_in[1];
    const float* c    = (const float*)d_in[2];
    const float* m    = (const float*)d_in[3];
    const float* kf   = (const float*)d_in[4];
    const float* cov  = (const float*)d_in[5];
    const float* win  = (const float*)d_in[6];
    const float* bin  = (const float*)d_in[7];
    const float* wg   = (const float*)d_in[8];
    const float* bg   = (const float*)d_in[9];
    const float* wm   = (const float*)d_in[10];
    const float* bm   = (const float*)d_in[11];
    const float* ecw  = (const float*)d_in[12];
    const float* ecb  = (const float*)d_in[13];
    const float* elw  = (const float*)d_in[14];
    const float* elb  = (const float*)d_in[15];
    const float* elg  = (const float*)d_in[16];
    const float* elbeta=(const float*)d_in[17];
    const float* dlw  = (const float*)d_in[18];
    const float* dlb  = (const float*)d_in[19];
    const float* dcw  = (const float*)d_in[20];
    const float* dcb  = (const float*)d_in[21];
    const float* flow = (const float*)d_in[22];
    const float* fhigh= (const float*)d_in[23];
    const float* nl1w = (const float*)d_in[24];
    const float* nl1b = (const float*)d_in[25];
    const float* lng  = (const float*)d_in[26];
    const float* lnb  = (const float*)d_in[27];
    const float* nl2w = (const float*)d_in[28];
    const float* nl2b = (const float*)d_in[29];
    const float* nlwt = (const float*)d_in[30];
    const float* logQ = (const float*)d_in[31];
    const float* logR = (const float*)d_in[32];
    const float* kfal = (const float*)d_in[33];
    const float* resw = (const float*)d_in[34];

    // f32 output layout: h_next, c_next, m_next each 8,388,608; kf 2048; cov 131072.
    float* out_h   = (float*)d_out;
    float* out_c   = out_h + 8388608;
    float* out_m   = out_c + 8388608;
    float* out_kf  = out_m + 8388608;
    float* out_cov = out_kf + 2048;

    // ZERO d_ws usage. Scratch lives in the out_m region (33.5 MB);
    // k_convm (sole writer of m_next) runs LAST and overwrites the full region.
    char* s = (char*)out_m;
    float* Wg    = (float*)(s);             // 1,769,472 B
    float* Wd    = (float*)(s + 1769472);   //    73,728 B
    float* We    = (float*)(s + 1843200);   //    73,728 B
    float* FmG   = (float*)(s + 1916928);   //    16,384 B
    float* FmT   = (float*)(s + 1933312);   //    16,384 B
    float* enc   = (float*)(s + 1949696);   //     8,192 B
    float* spred = (float*)(s + 1957888);   //     8,192 B
    float* kfn   = (float*)(s + 1966080);   //     8,192 B
    float* pP    = (float*)(s + 2097152);   // 2,097,152 B
    float* eE    = (float*)(s + 4194304);   // 1,048,576 B
    float* dlin  = (float*)(s + 5242880);   // 1,048,576 B  (6.3 MB < 33.5 MB)
    float* hlb   = out_h;                    // f32 h_lstm, updated in place by k_decconv

    k_reorg_wg<<<(110592+255)/256, 256, 0, stream>>>(wg, (float4*)Wg);
    k_reorg_conv<<<(18432+255)/256, 256, 0, stream>>>(dcw, Wd, 32, 64);
    k_reorg_conv<<<(18432+255)/256, 256, 0, stream>>>(ecw, We, 64, 32);
    k_fm<<<16, 256, 0, stream>>>(flow, fhigh, FmG, FmT);

    k_gates<<<2048, 256, 0, stream>>>(x, win, bin, h, m, c, (const float4*)Wg, bg, out_c, hlb);
    k_pool<<<2048, 256, 0, stream>>>(hlb, pP);
    k_encconv<<<512, 512, 0, stream>>>(pP, We, ecb, eE);
    k_enclin<<<32, 1024, 0, stream>>>(eE, elw, elb, elg, elbeta, enc);
    k_nlspred<<<32, 128, 0, stream>>>(kf, nl1w, nl1b, lng, lnb, nl2w, nl2b, nlwt, FmG, spred);
    k_ekf<<<32, 256, 0, stream>>>(cov, FmG, FmT, logQ, logR, enc, spred, kfn, out_kf, out_cov);
    k_declin<<<1024, 256, 0, stream>>>(kfn, dlw, dlb, dlin);
    k_decconv<<<2048, 256, 0, stream>>>(dlin, Wd, dcb, hlb, h, kfal, resw);
    k_convm<<<2048, 256, 0, stream>>>(out_c, wm, bm, out_m);
}

// Round 15
// 996.436 us; speedup vs baseline: 2.2498x; 2.2498x over previous
//
#include <hip/hip_runtime.h>
#include <hip/hip_bf16.h>

typedef unsigned int u32;
typedef unsigned short u16;
typedef __attribute__((ext_vector_type(8))) short bf16x8;
typedef __attribute__((ext_vector_type(4))) float f32x4;

constexpr int NHW = 4096;

// identity on sane data; maps NaN->0, clamps to +/-1e20
__device__ __forceinline__ float sanit(float v){
    v = (v == v) ? v : 0.0f;
    return fminf(fmaxf(v, -1e20f), 1e20f);
}
__device__ __forceinline__ u16 f2bu(float f){
    f = (f == f) ? f : 0.0f;
    u32 x = __float_as_uint(f);
    u32 r = x + 0x7fffu + ((x >> 16) & 1u);   // round-to-nearest-even
    return (u16)(r >> 16);
}
__device__ __forceinline__ float sigm(float x){ return 1.0f/(1.0f + expf(-x)); }
__device__ __forceinline__ float lrelu(float x){ return x > 0.f ? x : 0.01f*x; }

// ---------------- gates weights -> bf16 [m=hc*4+gate][k=(dy*3+dx)*192+ic] ----------------
__global__ __launch_bounds__(256) void k_reorg_wgb(const float* __restrict__ wg, u16* __restrict__ out){
    int idx = blockIdx.x*256 + threadIdx.x;   // 256*1728 = 442368
    if (idx >= 442368) return;
    int k = idx % 1728, mm = idx / 1728;
    int gate = mm & 3, hc = mm >> 2;
    int tap = k / 192, ic = k - tap*192;
    out[idx] = f2bu(sanit(wg[((gate*64 + hc)*192 + ic)*9 + tap]));
}

__global__ __launch_bounds__(256) void k_reorg_conv(const float* __restrict__ w, float* __restrict__ out,
                                                    int cin, int cout){
    // in [cout][cin][9] -> out [(ic*9+tap)*cout + oc]
    int idx = blockIdx.x*256 + threadIdx.x;
    if (idx >= cin*cout*9) return;
    int oc = idx % cout;
    int tap = (idx / cout) % 9;
    int ic = idx / (cout*9);
    out[idx] = sanit(w[(oc*cin + ic)*9 + tap]);
}

__global__ __launch_bounds__(256) void k_fm(const float* __restrict__ flow, const float* __restrict__ fhigh,
                                            float* __restrict__ Fm, float* __restrict__ FmT){
    int idx = blockIdx.x*256 + threadIdx.x;     // 4096
    if (idx >= 64*64) return;
    int j = idx & 63, i = idx >> 6;
    float s = (i==j) ? 1.0f : 0.0f;
    for (int t=0; t<24; ++t) s = fmaf(sanit(flow[i*24 + t]), sanit(fhigh[t*64 + j]), s);
    s = sanit(s);
    Fm[i*64+j] = s; FmT[j*64+i] = s;
}

// ---------------- gates conv as bf16 MFMA implicit GEMM + fused xproj + LSTM pointwise ----------------
// Per block: one (b, y). GEMM: M=256 (hc*4+gate), N=64 (x), K=1728 ((dy*3+dx)*192+ic).
// 3 phases (dy): stage haloed input row transposed T[x'][ch] bf16, run 18 K-steps.
// Wave w owns M-rows [w*64, w*64+64): 4 M-tiles x 4 N-tiles of 16x16x32 MFMA.
// C/D layout (col=lane&15, row=(lane>>4)*4+reg) => lane regs 0..3 = gates i,f,g,o of one (hc,x).
__global__ __launch_bounds__(256) void k_gates_mfma(
    const float* __restrict__ x, const float* __restrict__ win, const float* __restrict__ bin,
    const float* __restrict__ h, const float* __restrict__ m, const float* __restrict__ c,
    const u16* __restrict__ Wbf, const float* __restrict__ bg,
    float* __restrict__ c_out, float* __restrict__ hl_out)
{
    __shared__ __align__(16) u16 T[66*200];     // [x'=0..65][ch padded 192->200]
    const int bid = blockIdx.x;
    const int b = bid >> 6, y = bid & 63;
    const int t = threadIdx.x;
    const int lane = t & 63, w = t >> 6;
    const int q = lane >> 4, col = lane & 15;

    f32x4 acc[4][4];
    #pragma unroll
    for (int mt=0; mt<4; ++mt)
        #pragma unroll
        for (int nt=0; nt<4; ++nt)
            acc[mt][nt] = (f32x4){0.f,0.f,0.f,0.f};

    // A row base per M-tile: row m = w*64 + mt*16 + col, k-lane-offset q*8
    const u16* Abase[4];
    #pragma unroll
    for (int mt=0; mt<4; ++mt)
        Abase[mt] = Wbf + (w*64 + mt*16 + col)*1728 + q*8;

    for (int phase = 0; phase < 3; ++phase){
        int yin = y + phase - 1;
        __syncthreads();
        if (t < 192){
            int ch = t;
            T[0*200 + ch] = 0; T[65*200 + ch] = 0;      // x halo
            if ((unsigned)yin < 64u){
                if (ch < 64){
                    float wa = sanit(win[ch*3]), wb2 = sanit(win[ch*3+1]), wc = sanit(win[ch*3+2]);
                    float bi2 = sanit(bin[ch]);
                    const float* x0p = x + (b*3+0)*NHW + yin*64;
                    const float* x1p = x + (b*3+1)*NHW + yin*64;
                    const float* x2p = x + (b*3+2)*NHW + yin*64;
                    #pragma unroll 4
                    for (int x4 = 0; x4 < 16; ++x4){
                        float4 a0 = *(const float4*)(x0p + x4*4);
                        float4 a1 = *(const float4*)(x1p + x4*4);
                        float4 a2 = *(const float4*)(x2p + x4*4);
                        float v0 = fmaf(wa, sanit(a0.x), fmaf(wb2, sanit(a1.x), fmaf(wc, sanit(a2.x), bi2)));
                        float v1 = fmaf(wa, sanit(a0.y), fmaf(wb2, sanit(a1.y), fmaf(wc, sanit(a2.y), bi2)));
                        float v2 = fmaf(wa, sanit(a0.z), fmaf(wb2, sanit(a1.z), fmaf(wc, sanit(a2.z), bi2)));
                        float v3 = fmaf(wa, sanit(a0.w), fmaf(wb2, sanit(a1.w), fmaf(wc, sanit(a2.w), bi2)));
                        T[(x4*4+1)*200 + ch] = f2bu(v0);
                        T[(x4*4+2)*200 + ch] = f2bu(v1);
                        T[(x4*4+3)*200 + ch] = f2bu(v2);
                        T[(x4*4+4)*200 + ch] = f2bu(v3);
                    }
                } else {
                    const float* sp = (ch < 128 ? h + (b*64 + ch-64)*NHW : m + (b*64 + ch-128)*NHW) + yin*64;
                    #pragma unroll 4
                    for (int x4 = 0; x4 < 16; ++x4){
                        float4 a0 = *(const float4*)(sp + x4*4);
                        T[(x4*4+1)*200 + ch] = f2bu(sanit(a0.x));
                        T[(x4*4+2)*200 + ch] = f2bu(sanit(a0.y));
                        T[(x4*4+3)*200 + ch] = f2bu(sanit(a0.z));
                        T[(x4*4+4)*200 + ch] = f2bu(sanit(a0.w));
                    }
                }
            } else {
                for (int xi=0; xi<64; ++xi) T[(xi+1)*200 + ch] = 0;
            }
        }
        __syncthreads();

        // 18 K-steps: ksl = dx*6 + cg, k-global = (phase*18+ksl)*32
        #pragma unroll 1
        for (int ksl = 0; ksl < 18; ++ksl){
            int dx2 = ksl / 6;
            int c0  = (ksl - dx2*6)*32;
            int koff = (phase*18 + ksl)*32;
            bf16x8 af[4], bfv[4];
            #pragma unroll
            for (int mt=0; mt<4; ++mt)
                af[mt] = *(const bf16x8*)(Abase[mt] + koff);
            #pragma unroll
            for (int nt=0; nt<4; ++nt)
                bfv[nt] = *(const bf16x8*)&T[(nt*16 + col + dx2)*200 + c0 + q*8];
            #pragma unroll
            for (int mt=0; mt<4; ++mt)
                #pragma unroll
                for (int nt=0; nt<4; ++nt)
                    acc[mt][nt] = __builtin_amdgcn_mfma_f32_16x16x32_bf16(af[mt], bfv[nt], acc[mt][nt], 0, 0, 0);
        }
    }

    // epilogue: lane-local LSTM pointwise; regs 0..3 = i,f,g,o of (hc, x)
    #pragma unroll
    for (int mt=0; mt<4; ++mt){
        int hc = w*16 + mt*4 + q;
        float bi  = sanit(bg[hc]);
        float bff = sanit(bg[64+hc]);
        float bgg = sanit(bg[128+hc]);
        float bo  = sanit(bg[192+hc]);
        #pragma unroll
        for (int nt=0; nt<4; ++nt){
            int xpos = nt*16 + col;
            int idx = (b*64+hc)*NHW + y*64 + xpos;
            float civ = sanit(c[idx]);
            float iv = sigm(sanit(acc[mt][nt][0]) + bi);
            float fv = sigm(sanit(acc[mt][nt][1]) + bff);
            float gv = tanhf(sanit(acc[mt][nt][2]) + bgg);
            float ov = sigm(sanit(acc[mt][nt][3]) + bo);
            float cn = fv*civ + iv*gv;
            c_out[idx] = cn;
            hl_out[idx] = ov*tanhf(cn);
        }
    }
}

// ---------------- conv_m (64->64, 3x3) + m_next pointwise — runs LAST, reads f32 c_next ----------------
__global__ __launch_bounds__(256) void k_convm(
    const float* __restrict__ cnx, const float* __restrict__ wm, const float* __restrict__ bm,
    float* __restrict__ m_out)
{
    __shared__ float smem[64*3*68];
    const int bid = blockIdx.x;
    const int b = bid >> 6, y = bid & 63;
    const int t = threadIdx.x;
    const int oc = t & 63, xg = t >> 6, x0 = xg*16;

    for (int it = t; it < 64*3*68; it += 256){
        int icl = it / 204;
        int rem = it - icl*204;
        int dy = rem / 68;
        int xi = rem - dy*68;
        int xx = xi - 1, ys = y + dy - 1;
        float v = 0.f;
        if (((unsigned)xx < 64u) && ((unsigned)ys < 64u))
            v = cnx[(b*64+icl)*NHW + ys*64 + xx];
        smem[it] = v;
    }
    __syncthreads();

    float acc[16];
    #pragma unroll
    for (int i=0;i<16;++i) acc[i]=0.f;
    #pragma unroll 1
    for (int ic=0; ic<64; ++ic){
        const float* wrow = wm + (oc*64 + ic)*9;
        #pragma unroll
        for (int dy=0; dy<3; ++dy){
            float r[20];
            const float4* rp = (const float4*)(&smem[ic*204 + dy*68 + x0]);
            #pragma unroll
            for (int q=0;q<5;++q){ float4 v4=rp[q]; r[4*q]=v4.x;r[4*q+1]=v4.y;r[4*q+2]=v4.z;r[4*q+3]=v4.w; }
            #pragma unroll
            for (int dx=0; dx<3; ++dx){
                float wv = sanit(wrow[dy*3 + dx]);
                #pragma unroll
                for (int xx=0; xx<16; ++xx) acc[xx] = fmaf(wv, r[xx+dx], acc[xx]);
            }
        }
    }
    float bmv = sanit(bm[oc]);
    const int base = (b*64+oc)*NHW + y*64 + x0;
    float cv[16];
    { const float4* cp = (const float4*)(cnx + base);
      #pragma unroll
      for (int q=0;q<4;++q){ float4 v4=cp[q]; cv[4*q]=v4.x;cv[4*q+1]=v4.y;cv[4*q+2]=v4.z;cv[4*q+3]=v4.w; } }
    float4* mo = (float4*)(m_out + base);
    #pragma unroll
    for (int q=0;q<4;++q){
        float m0 = sigm(sanit(acc[4*q+0])+bmv)*tanhf(cv[4*q+0]);
        float m1 = sigm(sanit(acc[4*q+1])+bmv)*tanhf(cv[4*q+1]);
        float m2 = sigm(sanit(acc[4*q+2])+bmv)*tanhf(cv[4*q+2]);
        float m3 = sigm(sanit(acc[4*q+3])+bmv)*tanhf(cv[4*q+3]);
        mo[q] = make_float4(m0,m1,m2,m3);
    }
}

// ---------------- 4x4 avg pool (reads f32 h_lstm) ----------------
__global__ __launch_bounds__(256) void k_pool(const float* __restrict__ hl, float* __restrict__ p){
    int idx = blockIdx.x*256 + threadIdx.x;     // 32*64*256
    int px = idx & 15, py = (idx>>4) & 15, ch = (idx>>8) & 63, b = idx >> 14;
    const float* src = hl + (b*64+ch)*NHW + (py*4)*64 + px*4;
    float s = 0.f;
    #pragma unroll
    for (int dy=0;dy<4;++dy)
        #pragma unroll
        for (int dx=0;dx<4;++dx) s += src[dy*64 + dx];
    p[idx] = s * 0.0625f;
}

// ---------------- encoder conv (64->32, 3x3 on 16x16) ----------------
__global__ __launch_bounds__(512) void k_encconv(const float* __restrict__ p, const float* __restrict__ We,
        const float* __restrict__ bb, float* __restrict__ e){
    __shared__ float smem[64*3*18];
    int bid = blockIdx.x;
    int b = bid >> 4, py = bid & 15;
    int t = threadIdx.x;
    for (int it = t; it < 64*3*18; it += 512){
        int ic = it / 54;
        int rem = it - ic*54;
        int dy = rem / 18;
        int xi = rem - dy*18;
        int xx = xi-1, ys = py+dy-1;
        float v = 0.f;
        if (((unsigned)xx<16u)&&((unsigned)ys<16u)) v = p[(b*64+ic)*256 + ys*16+xx];
        smem[it] = v;
    }
    __syncthreads();
    int oc = t & 31, px = t >> 5;
    float acc = sanit(bb[oc]);
    #pragma unroll 1
    for (int ic=0; ic<64; ++ic){
        #pragma unroll
        for (int dy=0; dy<3; ++dy){
            const float* row = &smem[ic*54 + dy*18];
            #pragma unroll
            for (int dx=0; dx<3; ++dx)
                acc = fmaf(We[(ic*9+dy*3+dx)*32 + oc], row[px+dx], acc);
        }
    }
    e[b*8192 + oc*256 + py*16 + px] = lrelu(sanit(acc));
}

// ---------------- encoder linear 8192->64 + LayerNorm (f32 weights) ----------------
__global__ __launch_bounds__(1024) void k_enclin(const float* __restrict__ e, const float* __restrict__ elw,
        const float* __restrict__ lb, const float* __restrict__ lg, const float* __restrict__ lbeta,
        float* __restrict__ enc){
    __shared__ float sums[16*64];
    int b = blockIdx.x;
    int t = threadIdx.x;
    int s = t & 63, part = t >> 6;
    float acc = 0.f;
    const float* eb = e + b*8192 + part*512;
    const float* wb = elw + s*8192 + part*512;
    for (int k=0; k<512; ++k)
        acc = fmaf(eb[k], sanit(wb[k]), acc);
    sums[part*64 + s] = acc;
    __syncthreads();
    if (t < 64){
        float v = sanit(lb[t]);
        #pragma unroll
        for (int q=0;q<16;++q) v += sums[q*64 + t];
        v = sanit(v);
        float sm = v, sq = v*v;
        #pragma unroll
        for (int o=32;o>=1;o>>=1){ sm += __shfl_xor(sm,o,64); sq += __shfl_xor(sq,o,64); }
        float mu = sm*(1.f/64.f);
        float var = fmaxf(sq*(1.f/64.f) - mu*mu, 0.f);
        enc[b*64+t] = sanit((v-mu)*rsqrtf(var+1e-5f)*sanit(lg[t])+sanit(lbeta[t]));
    }
}

// ---------------- KF nonlinearity + state_pred ----------------
__global__ __launch_bounds__(128) void k_nlspred(const float* __restrict__ kf,
        const float* __restrict__ nl1w, const float* __restrict__ nl1b,
        const float* __restrict__ lng, const float* __restrict__ lnb,
        const float* __restrict__ nl2w, const float* __restrict__ nl2b,
        const float* __restrict__ nlweight, const float* __restrict__ Fm,
        float* __restrict__ spred){
    __shared__ float ks[64], hid[128], hln[128];
    int b = blockIdx.x, t = threadIdx.x;
    if (t < 64) ks[t] = sanit(kf[b*64 + t]);
    __syncthreads();
    {
        float a = sanit(nl1b[t]);
        for (int k=0;k<64;++k) a = fmaf(ks[k], sanit(nl1w[t*64 + k]), a);
        hid[t] = sanit(a);
    }
    __syncthreads();
    {
        float sm=0.f, sq=0.f;
        for (int k=0;k<128;++k){ float v=hid[k]; sm+=v; sq+=v*v; }
        float mu = sm*(1.f/128.f), var = fmaxf(sq*(1.f/128.f)-mu*mu, 0.f);
        float nv = (hid[t]-mu)*rsqrtf(var+1e-5f)*sanit(lng[t])+sanit(lnb[t]);
        hln[t] = lrelu(sanit(nv));
    }
    __syncthreads();
    if (t < 64){
        float a = sanit(nl2b[t]);
        for (int k=0;k<128;++k) a = fmaf(hln[k], sanit(nl2w[t*128 + k]), a);
        float sp = sigm(sanit(nlweight[0])) * tanhf(sanit(a));
        for (int k=0;k<64;++k) sp = fmaf(ks[k], sanit(Fm[t*64+k]), sp);
        spred[b*64+t] = sanit(sp);
    }
}

// ---------------- EKF core (f32 in/out) ----------------
__global__ __launch_bounds__(256) void k_ekf(
    const float* __restrict__ kfcov, const float* __restrict__ FmG, const float* __restrict__ FmTG,
    const float* __restrict__ logQ, const float* __restrict__ logR,
    const float* __restrict__ enc, const float* __restrict__ spred,
    float* __restrict__ kfn_f32, float* __restrict__ kfs_out, float* __restrict__ cov_out)
{
    __shared__ float A[64*65];
    __shared__ float P[64*65];
    __shared__ float Sm[64*65];
    __shared__ float rdv[64], innov[64], fcol[64];
    int b = blockIdx.x, t = threadIdx.x;
    int j = t & 63, ig = t >> 6;

    for (int o=t; o<4096; o+=256){
        int k = o >> 6, jj = o & 63;
        A[k*65+jj] = sanit(kfcov[b*4096 + o]);
    }
    if (t < 64){
        rdv[t] = sanit(expf(sanit(logR[t])));
        innov[t] = sanit(sanit(enc[b*64+t]) - sanit(spred[b*64+t]));
    }
    __syncthreads();

    float acc[16];
    #pragma unroll
    for (int r=0;r<16;++r) acc[r]=0.f;
    for (int k=0;k<64;++k){
        float cv = A[k*65+j];
        #pragma unroll
        for (int r=0;r<16;++r) acc[r] = fmaf(sanit(FmG[(ig*16+r)*64+k]), cv, acc[r]);
    }
    __syncthreads();
    #pragma unroll
    for (int r=0;r<16;++r) A[(ig*16+r)*65+j] = sanit(acc[r]);
    __syncthreads();

    #pragma unroll
    for (int r=0;r<16;++r) acc[r]=0.f;
    for (int k=0;k<64;++k){
        float fv = sanit(FmTG[k*64+j]);
        #pragma unroll
        for (int r=0;r<16;++r) acc[r] = fmaf(A[(ig*16+r)*65+k], fv, acc[r]);
    }
    #pragma unroll
    for (int r=0;r<16;++r){
        int i = ig*16+r;
        float v = sanit(acc[r]);
        if (i==j) v += sanit(expf(sanit(logQ[i])));
        P[i*65+j] = v;
        Sm[i*65+j] = v + ((i==j) ? (rdv[j] + 1e-5f) : 0.f);
    }
    __syncthreads();

    for (int k=0;k<64;++k){
        float d = Sm[k*65+k];
        if (fabsf(d) < 1e-20f) d = (d < 0.f) ? -1e-20f : 1e-20f;
        float pv = 1.0f / d;
        float skj = (j==k) ? pv : Sm[k*65+j]*pv;
        if (ig == 0) fcol[j] = Sm[j*65+k];
        __syncthreads();
        #pragma unroll
        for (int r=0;r<16;++r){
            int i = ig*16+r;
            float nv;
            if (i == k)      nv = skj;
            else if (j == k) nv = -fcol[i]*pv;
            else             nv = fmaf(-fcol[i], skj, Sm[i*65+j]);
            Sm[i*65+j] = sanit(nv);
        }
        __syncthreads();
    }

    #pragma unroll
    for (int r=0;r<16;++r) acc[r]=0.f;
    for (int k=0;k<64;++k){
        float sv = Sm[k*65+j];
        #pragma unroll
        for (int r=0;r<16;++r) acc[r] = fmaf(P[(ig*16+r)*65+k], sv, acc[r]);
    }
    __syncthreads();
    #pragma unroll
    for (int r=0;r<16;++r) A[(ig*16+r)*65+j] = sanit(acc[r]);
    __syncthreads();

    if (t < 64){
        float kn = sanit(spred[b*64+t]);
        for (int k2=0;k2<64;++k2) kn = fmaf(A[t*65+k2], innov[k2], kn);
        kn = sanit(kn);
        kfn_f32[b*64+t] = kn;
        kfs_out[b*64+t] = kn;
    }

    #pragma unroll
    for (int r=0;r<16;++r) acc[r]=0.f;
    for (int k=0;k<64;++k){
        float pvj = P[k*65+j];
        #pragma unroll
        for (int r=0;r<16;++r) acc[r] = fmaf(A[(ig*16+r)*65+k], pvj, acc[r]);
    }
    __syncthreads();
    #pragma unroll
    for (int r=0;r<16;++r) Sm[(ig*16+r)*65+j] = sanit(P[(ig*16+r)*65+j] - acc[r]);
    __syncthreads();

    #pragma unroll
    for (int r=0;r<16;++r){
        int i = ig*16+r;
        float s1 = 0.f, s2 = 0.f;
        for (int k=0;k<64;++k){
            float kjk = A[j*65+k];
            s1 = fmaf(Sm[i*65+k], kjk, s1);
            s2 = fmaf(A[i*65+k]*rdv[k], kjk, s2);
        }
        cov_out[b*4096 + i*64 + j] = sanit(Sm[i*65+j] - s1 + s2);
    }
}

// ---------------- decoder linear 64->8192 (f32 weights) ----------------
__global__ __launch_bounds__(256) void k_declin(const float* __restrict__ kfn, const float* __restrict__ dlw,
        const float* __restrict__ db, float* __restrict__ dlin){
    __shared__ float ks[64];
    int bid = blockIdx.x;
    int b = bid >> 5;
    int j = (bid & 31)*256 + threadIdx.x;
    if (threadIdx.x < 64) ks[threadIdx.x] = sanit(kfn[b*64 + threadIdx.x]);
    __syncthreads();
    float a = sanit(db[j]);
    const float* wr = dlw + j*64;
    for (int k=0;k<64;++k) a = fmaf(ks[k], sanit(wr[k]), a);
    dlin[b*8192 + j] = lrelu(sanit(a));
}

// ---------------- decoder conv (32->64, 3x3) + fused bilinear upsample + final h_next ----------------
__global__ __launch_bounds__(256) void k_decconv(
    const float* __restrict__ dlin, const float* __restrict__ Wd, const float* __restrict__ bd,
    float* hbuf, const float* __restrict__ horig,
    const float* __restrict__ alpha_p, const float* __restrict__ resw_p)
{
    __shared__ float smem[32*3*68];
    int bid = blockIdx.x;
    int b = bid >> 6, y = bid & 63;
    int t = threadIdx.x;
    int oc = t & 63, xg = t >> 6, x0 = xg*16;

    for (int it=t; it<32*3*68; it+=256){
        int icl = it / 204;
        int rem = it - icl*204;
        int dy = rem / 68;
        int xi = rem - dy*68;
        int xx = xi-1, ys = y+dy-1;
        float v = 0.f;
        if (((unsigned)xx<64u)&&((unsigned)ys<64u)){
            float sy = (ys + 0.5f)*0.25f - 0.5f;
            float sx = (xx + 0.5f)*0.25f - 0.5f;
            float y0f = floorf(sy), x0f = floorf(sx);
            float fy = sy - y0f, fx = sx - x0f;
            int y0 = (int)y0f, x0i = (int)x0f;
            int y1 = min(max(y0+1,0),15), x1 = min(max(x0i+1,0),15);
            y0 = min(max(y0,0),15); x0i = min(max(x0i,0),15);
            const float* dp = dlin + (b*32+icl)*256;
            float v00 = sanit(dp[y0*16+x0i]), v01 = sanit(dp[y0*16+x1]);
            float v10 = sanit(dp[y1*16+x0i]), v11 = sanit(dp[y1*16+x1]);
            float va = v00 + fx*(v01-v00);
            float vb = v10 + fx*(v11-v10);
            v = va + fy*(vb-va);
        }
        smem[it] = v;
    }
    __syncthreads();

    float acc[16];
    #pragma unroll
    for (int i=0;i<16;++i) acc[i]=0.f;
    #pragma unroll 1
    for (int ic=0; ic<32; ++ic){
        #pragma unroll
        for (int dy=0; dy<3; ++dy){
            float r[20];
            const float4* rp = (const float4*)(&smem[ic*204 + dy*68 + x0]);
            #pragma unroll
            for (int q=0;q<5;++q){ float4 v4=rp[q]; r[4*q]=v4.x;r[4*q+1]=v4.y;r[4*q+2]=v4.z;r[4*q+3]=v4.w; }
            #pragma unroll
            for (int dx=0; dx<3; ++dx){
                float wv = sanit(Wd[(ic*9+dy*3+dx)*64 + oc]);
                #pragma unroll
                for (int xx=0;xx<16;++xx) acc[xx] = fmaf(wv, r[xx+dx], acc[xx]);
            }
        }
    }
    float bdv = sanit(bd[oc]);
    float alpha = sigm(sanit(alpha_p[0]));
    float resw = sigm(sanit(resw_p[0]));
    int base = (b*64+oc)*NHW + y*64 + x0;
    float hlv[16], hov[16];
    { const float4* hp2 = (const float4*)(hbuf + base);
      #pragma unroll
      for (int q=0;q<4;++q){ float4 v4=hp2[q]; hlv[4*q]=v4.x;hlv[4*q+1]=v4.y;hlv[4*q+2]=v4.z;hlv[4*q+3]=v4.w; } }
    { const float4* gp = (const float4*)(horig + base);
      #pragma unroll
      for (int q=0;q<4;++q){ float4 v4=gp[q]; hov[4*q]=v4.x;hov[4*q+1]=v4.y;hov[4*q+2]=v4.z;hov[4*q+3]=v4.w; } }
    float hn[16];
    #pragma unroll
    for (int xx=0; xx<16; ++xx){
        float dec = lrelu(sanit(acc[xx]+bdv));
        hn[xx] = hlv[xx]*(1.f-alpha) + dec*alpha + resw*sanit(hov[xx]);
    }
    float4* hp = (float4*)(hbuf + base);
    #pragma unroll
    for (int q=0;q<4;++q)
        hp[q] = make_float4(hn[4*q], hn[4*q+1], hn[4*q+2], hn[4*q+3]);
}

extern "C" void kernel_launch(void* const* d_in, const int* in_sizes, int n_in,
                              void* d_out, int out_size, void* d_ws, size_t ws_size,
                              hipStream_t stream)
{
    (void)in_sizes; (void)n_in; (void)out_size; (void)d_ws; (void)ws_size;
    const float* x    = (const float*)d_in[0];
    const float* h    = (const float*)d_in[1];
    const float* c    = (const float*)d_in[2];
    const float* m    = (const float*)d_in[3];
    const float* kf   = (const float*)d_in[4];
    const float* cov  = (const float*)d_in[5];
    const float* win  = (const float*)d_in[6];
    const float* bin  = (const float*)d_in[7];
    const float* wg   = (const float*)d_in[8];
    const float* bg   = (const float*)d_in[9];
    const float* wm   = (const float*)d_in[10];
    const float* bm   = (const float*)d_in[11];
    const float* ecw  = (const float*)d_in[12];
    const float* ecb  = (const float*)d_in[13];
    const float* elw  = (const float*)d_in[14];
    const float* elb  = (const float*)d_in[15];
    const float* elg  = (const float*)d_in[16];
    const float* elbeta=(const float*)d_in[17];
    const float* dlw  = (const float*)d_in[18];
    const float* dlb  = (const float*)d_in[19];
    const float* dcw  = (const float*)d_in[20];
    const float* dcb  = (const float*)d_in[21];
    const float* flow = (const float*)d_in[22];
    const float* fhigh= (const float*)d_in[23];
    const float* nl1w = (const float*)d_in[24];
    const float* nl1b = (const float*)d_in[25];
    const float* lng  = (const float*)d_in[26];
    const float* lnb  = (const float*)d_in[27];
    const float* nl2w = (const float*)d_in[28];
    const float* nl2b = (const float*)d_in[29];
    const float* nlwt = (const float*)d_in[30];
    const float* logQ = (const float*)d_in[31];
    const float* logR = (const float*)d_in[32];
    const float* kfal = (const float*)d_in[33];
    const float* resw = (const float*)d_in[34];

    float* out_h   = (float*)d_out;
    float* out_c   = out_h + 8388608;
    float* out_m   = out_c + 8388608;
    float* out_kf  = out_m + 8388608;
    float* out_cov = out_kf + 2048;

    // ZERO d_ws usage. Scratch in out_m region (33.5 MB); k_convm runs LAST.
    char* s = (char*)out_m;
    u16*   Wbf   = (u16*)(s);               //   884,736 B (bf16 gates weights)
    float* Wd    = (float*)(s + 1769472);   //    73,728 B
    float* We    = (float*)(s + 1843200);   //    73,728 B
    float* FmG   = (float*)(s + 1916928);   //    16,384 B
    float* FmT   = (float*)(s + 1933312);   //    16,384 B
    float* enc   = (float*)(s + 1949696);   //     8,192 B
    float* spred = (float*)(s + 1957888);   //     8,192 B
    float* kfn   = (float*)(s + 1966080);   //     8,192 B
    float* pP    = (float*)(s + 2097152);   // 2,097,152 B
    float* eE    = (float*)(s + 4194304);   // 1,048,576 B
    float* dlin  = (float*)(s + 5242880);   // 1,048,576 B
    float* hlb   = out_h;                    // f32 h_lstm, updated in place by k_decconv

    k_reorg_wgb<<<1728, 256, 0, stream>>>(wg, Wbf);
    k_reorg_conv<<<(18432+255)/256, 256, 0, stream>>>(dcw, Wd, 32, 64);
    k_reorg_conv<<<(18432+255)/256, 256, 0, stream>>>(ecw, We, 64, 32);
    k_fm<<<16, 256, 0, stream>>>(flow, fhigh, FmG, FmT);

    k_gates_mfma<<<2048, 256, 0, stream>>>(x, win, bin, h, m, c, Wbf, bg, out_c, hlb);
    k_pool<<<2048, 256, 0, stream>>>(hlb, pP);
    k_encconv<<<512, 512, 0, stream>>>(pP, We, ecb, eE);
    k_enclin<<<32, 1024, 0, stream>>>(eE, elw, elb, elg, elbeta, enc);
    k_nlspred<<<32, 128, 0, stream>>>(kf, nl1w, nl1b, lng, lnb, nl2w, nl2b, nlwt, FmG, spred);
    k_ekf<<<32, 256, 0, stream>>>(cov, FmG, FmT, logQ, logR, enc, spred, kfn, out_kf, out_cov);
    k_declin<<<1024, 256, 0, stream>>>(kfn, dlw, dlb, dlin);
    k_decconv<<<2048, 256, 0, stream>>>(dlin, Wd, dcb, hlb, h, kfal, resw);
    k_convm<<<2048, 256, 0, stream>>>(out_c, wm, bm, out_m);
}